// Round 1
// baseline (314.908 us; speedup 1.0000x reference)
//
#include <hip/hip_runtime.h>
#include <math.h>

#define NB 1024
#define CHN 5

static constexpr int kN = 512 * 512;        // 262144 pixels
static constexpr int kB = 16;
static constexpr int kChunks = 64;
static constexpr int kThreads = 256;
static constexpr int kF4PerBlock = (kN / kChunks) / 4;  // 1024 float4 groups per block
static constexpr int kGroups = kF4PerBlock / kThreads;  // 4 per thread

// workspace layout (bytes):
//   [0,1024):            float scal[16][16]
//     per batch: 0=total, 1..4=class sums, 5=sev sum, 6=damaged cnt, 7=high cnt,
//                8..11=class max (float bits), 12=sev max (float bits)
//   [1024, +16*5*1024*4):   unsigned hist_cnt[16][5][1024]
//   [..,  +16*5*1024*4):    float    hist_sum[16][5][1024]
static constexpr size_t SCAL_OFF = 0;
static constexpr size_t HCNT_OFF = 1024;
static constexpr size_t HSUM_OFF = HCNT_OFF + (size_t)kB * CHN * NB * 4;
static constexpr size_t WS_BYTES = HSUM_OFF + (size_t)kB * CHN * NB * 4;

__global__ __launch_bounds__(kThreads) void ep_pass1(
    const float* __restrict__ logits,
    const float* __restrict__ sevmap,
    const float* __restrict__ mask,
    float* __restrict__ scal,
    unsigned* __restrict__ g_hcnt,
    float* __restrict__ g_hsum) {
  __shared__ unsigned s_hcnt[CHN * NB];   // 20 KB
  __shared__ float    s_hsum[CHN * NB];   // 20 KB

  const int tid = threadIdx.x;
  const int b = blockIdx.y;
  const int chunk = blockIdx.x;

  for (int i = tid; i < CHN * NB; i += kThreads) {
    s_hcnt[i] = 0u;
    s_hsum[i] = 0.f;
  }
  __syncthreads();

  const float4* L0 = (const float4*)(logits + (size_t)b * 4 * kN);
  const float4* L1 = L0 + kN / 4;
  const float4* L2 = L1 + kN / 4;
  const float4* L3 = L2 + kN / 4;
  const float4* SV = (const float4*)(sevmap + (size_t)b * kN);
  const float4* MK = (const float4*)(mask + (size_t)b * kN);
  const int base = chunk * kF4PerBlock;

  float cnt = 0.f, sum0 = 0.f, sum1 = 0.f, sum2 = 0.f, sum3 = 0.f;
  float sevs = 0.f, dmg = 0.f, hig = 0.f;
  float mx0 = 0.f, mx1 = 0.f, mx2 = 0.f, mx3 = 0.f, sevm = 0.f;

  for (int g = 0; g < kGroups; ++g) {
    const int fi = base + g * kThreads + tid;
    float4 a = L0[fi];
    float4 bq = L1[fi];
    float4 cq = L2[fi];
    float4 dq = L3[fi];
    float4 sv = SV[fi];
    float4 mk = MK[fi];
#pragma unroll
    for (int j = 0; j < 4; ++j) {
      float l0 = ((const float*)&a)[j];
      float l1 = ((const float*)&bq)[j];
      float l2 = ((const float*)&cq)[j];
      float l3 = ((const float*)&dq)[j];
      float mv = fmaxf(fmaxf(l0, l1), fmaxf(l2, l3));
      float e0 = __expf(l0 - mv);
      float e1 = __expf(l1 - mv);
      float e2 = __expf(l2 - mv);
      float e3 = __expf(l3 - mv);
      float inv = 1.f / (e0 + e1 + e2 + e3);
      float p0 = e0 * inv, p1 = e1 * inv, p2 = e2 * inv, p3 = e3 * inv;
      float sg = 1.f / (1.f + __expf(-((const float*)&sv)[j]));
      bool valid = ((const float*)&mk)[j] > 0.5f;
      if (valid) {
        cnt += 1.f;
        sum0 += p0; sum1 += p1; sum2 += p2; sum3 += p3;
        mx0 = fmaxf(mx0, p0); mx1 = fmaxf(mx1, p1);
        mx2 = fmaxf(mx2, p2); mx3 = fmaxf(mx3, p3);
        sevs += sg; sevm = fmaxf(sevm, sg);
        dmg += (p1 + p2 + p3 > 0.25f) ? 1.f : 0.f;
        hig += (p2 + p3 > 0.25f) ? 1.f : 0.f;
        int bi0 = min(NB - 1, (int)(p0 * (float)NB));
        int bi1 = min(NB - 1, (int)(p1 * (float)NB));
        int bi2 = min(NB - 1, (int)(p2 * (float)NB));
        int bi3 = min(NB - 1, (int)(p3 * (float)NB));
        int bi4 = min(NB - 1, (int)(sg * (float)NB));
        atomicAdd(&s_hcnt[0 * NB + bi0], 1u); atomicAdd(&s_hsum[0 * NB + bi0], p0);
        atomicAdd(&s_hcnt[1 * NB + bi1], 1u); atomicAdd(&s_hsum[1 * NB + bi1], p1);
        atomicAdd(&s_hcnt[2 * NB + bi2], 1u); atomicAdd(&s_hsum[2 * NB + bi2], p2);
        atomicAdd(&s_hcnt[3 * NB + bi3], 1u); atomicAdd(&s_hsum[3 * NB + bi3], p3);
        atomicAdd(&s_hcnt[4 * NB + bi4], 1u); atomicAdd(&s_hsum[4 * NB + bi4], sg);
      }
    }
  }

  // wave-level scalar reduction, then one global atomic per wave
  float acc[8] = {cnt, sum0, sum1, sum2, sum3, sevs, dmg, hig};
  float mxs[5] = {mx0, mx1, mx2, mx3, sevm};
#pragma unroll
  for (int off = 32; off > 0; off >>= 1) {
#pragma unroll
    for (int i = 0; i < 8; ++i) acc[i] += __shfl_down(acc[i], off);
#pragma unroll
    for (int i = 0; i < 5; ++i) mxs[i] = fmaxf(mxs[i], __shfl_down(mxs[i], off));
  }
  const int lane = tid & 63;
  if (lane == 0) {
    float* Sb = scal + b * 16;
    unsigned* Su = (unsigned*)Sb;
#pragma unroll
    for (int i = 0; i < 8; ++i) atomicAdd(&Sb[i], acc[i]);
#pragma unroll
    for (int i = 0; i < 5; ++i) atomicMax(&Su[8 + i], __float_as_uint(mxs[i]));
  }
  __syncthreads();

  // merge LDS histograms into global
  unsigned* gh = g_hcnt + (size_t)b * CHN * NB;
  float* gs = g_hsum + (size_t)b * CHN * NB;
  for (int i = tid; i < CHN * NB; i += kThreads) {
    unsigned c = s_hcnt[i];
    if (c) {
      atomicAdd(&gh[i], c);
      atomicAdd(&gs[i], s_hsum[i]);
    }
  }
}

__global__ __launch_bounds__(256) void ep_finalize(
    const float* __restrict__ scal,
    const unsigned* __restrict__ g_hcnt,
    const float* __restrict__ g_hsum,
    const float* __restrict__ ln_w, const float* __restrict__ ln_b,
    const float* __restrict__ w1, const float* __restrict__ b1,
    const float* __restrict__ w2, const float* __restrict__ b2,
    float* __restrict__ out) {
  __shared__ float wtot_c[4], wtot_s[4];
  __shared__ float topk[CHN];
  __shared__ float stats[18], normed[18], h1v[256];

  const int tid = threadIdx.x;
  const int lane = tid & 63;
  const int wv = tid >> 6;
  const int b = blockIdx.x;
  const float* Sb = scal + b * 16;
  const unsigned* Su = (const unsigned*)Sb;

  const float total = Sb[0];
  const bool has = total > 0.f;
  const float safe = fmaxf(total, 1.f);
  const float kf = fmaxf(1.f, rintf(total * 0.1f));

  if (tid < CHN) topk[tid] = 0.f;

  for (int c = 0; c < CHN; ++c) {
    const unsigned* hc = g_hcnt + ((size_t)b * CHN + c) * NB;
    const float* hs = g_hsum + ((size_t)b * CHN + c) * NB;
    // thread tid owns 4-bin group (255 - tid): ascending tid = descending value bins
    uint4 cb4 = ((const uint4*)hc)[255 - tid];
    float4 sb4 = ((const float4*)hs)[255 - tid];
    float c0 = (float)cb4.x, c1 = (float)cb4.y, c2 = (float)cb4.z, c3 = (float)cb4.w;
    float gc = c0 + c1 + c2 + c3;
    float gsm = sb4.x + sb4.y + sb4.z + sb4.w;

    // inclusive scan within wave (ascending tid = from top of value range)
    float ic = gc, is = gsm;
#pragma unroll
    for (int off = 1; off < 64; off <<= 1) {
      float tc = __shfl_up(ic, off);
      float ts = __shfl_up(is, off);
      if (lane >= off) { ic += tc; is += ts; }
    }
    if (lane == 63) { wtot_c[wv] = ic; wtot_s[wv] = is; }
    __syncthreads();
    float basec = 0.f, bases = 0.f;
    for (int w = 0; w < wv; ++w) { basec += wtot_c[w]; bases += wtot_s[w]; }
    float ec = basec + ic - gc;   // count in bins strictly above this group
    float es = bases + is - gsm;  // sum   in bins strictly above this group

    if (has && ec < kf && kf <= ec + gc) {
      float cg = ec, sg2 = es;
      float cb[4] = {c3, c2, c1, c0};
      float sb[4] = {sb4.w, sb4.z, sb4.y, sb4.x};
#pragma unroll
      for (int q = 0; q < 4; ++q) {
        if (cg + cb[q] >= kf) {
          float r = kf - cg;
          float meanv = sb[q] / fmaxf(cb[q], 1.f);
          topk[c] = (sg2 + r * meanv) / kf;
          break;
        }
        cg += cb[q];
        sg2 += sb[q];
      }
    }
    __syncthreads();
  }

  if (tid == 0) {
    float inv_safe = 1.f / safe;
    stats[0] = Sb[1] * inv_safe;
    stats[1] = Sb[2] * inv_safe;
    stats[2] = Sb[3] * inv_safe;
    stats[3] = Sb[4] * inv_safe;
#pragma unroll
    for (int c = 0; c < 4; ++c) stats[4 + c] = has ? __uint_as_float(Su[8 + c]) : 0.f;
#pragma unroll
    for (int c = 0; c < 4; ++c) stats[8 + c] = has ? topk[c] : 0.f;
    stats[12] = has ? Sb[5] * inv_safe : 0.f;
    stats[13] = has ? __uint_as_float(Su[12]) : 0.f;
    stats[14] = has ? topk[4] : 0.f;
    stats[15] = has ? Sb[6] * inv_safe : 0.f;
    stats[16] = has ? Sb[7] * inv_safe : 0.f;
    stats[17] = has ? total * (1.f / (float)kN) : 0.f;

    float mu = 0.f;
#pragma unroll
    for (int i = 0; i < 18; ++i) mu += stats[i];
    mu *= (1.f / 18.f);
    float var = 0.f;
#pragma unroll
    for (int i = 0; i < 18; ++i) {
      float d = stats[i] - mu;
      var += d * d;
    }
    var *= (1.f / 18.f);
    float inv_std = rsqrtf(var + 1e-5f);
#pragma unroll
    for (int i = 0; i < 18; ++i)
      normed[i] = (stats[i] - mu) * inv_std * ln_w[i] + ln_b[i];
  }
  __syncthreads();

  // h1 = gelu_exact(normed @ w1 + b1)
  float x = b1[tid];
#pragma unroll
  for (int i = 0; i < 18; ++i) x += normed[i] * w1[i * 256 + tid];
  h1v[tid] = 0.5f * x * (1.f + erff(x * 0.70710678118654752440f));
  __syncthreads();

  // projected = h1 @ w2 + b2
  float y = b2[tid];
  for (int i = 0; i < 256; ++i) y += h1v[i] * w2[i * 256 + tid];

  // outputs: stats[16][18] | projected[16][256] | damaged[16] | high[16] | tar[16]
  out[288 + b * 256 + tid] = y;
  if (tid < 18) out[b * 18 + tid] = stats[tid];
  if (tid == 0) {
    out[4384 + b] = stats[15];
    out[4400 + b] = stats[16];
    out[4416 + b] = stats[17];
  }
}

extern "C" void kernel_launch(void* const* d_in, const int* in_sizes, int n_in,
                              void* d_out, int out_size, void* d_ws, size_t ws_size,
                              hipStream_t stream) {
  const float* logits = (const float*)d_in[0];
  const float* sevmap = (const float*)d_in[1];
  const float* maskp  = (const float*)d_in[2];
  const float* ln_w   = (const float*)d_in[3];
  const float* ln_b   = (const float*)d_in[4];
  const float* w1     = (const float*)d_in[5];
  const float* b1     = (const float*)d_in[6];
  const float* w2     = (const float*)d_in[7];
  const float* b2     = (const float*)d_in[8];
  float* out = (float*)d_out;

  char* ws = (char*)d_ws;
  float* scal = (float*)(ws + SCAL_OFF);
  unsigned* hcnt = (unsigned*)(ws + HCNT_OFF);
  float* hsum = (float*)(ws + HSUM_OFF);

  hipMemsetAsync(d_ws, 0, WS_BYTES, stream);

  dim3 g1(kChunks, kB);
  ep_pass1<<<g1, kThreads, 0, stream>>>(logits, sevmap, maskp, scal, hcnt, hsum);
  ep_finalize<<<kB, 256, 0, stream>>>(scal, hcnt, hsum, ln_w, ln_b, w1, b1, w2, b2, out);
}